// Round 5
// baseline (515.230 us; speedup 1.0000x reference)
//
#include <hip/hip_runtime.h>

#define N_NODES 50000
#define N_EDGES 800000
#define IN_FEAT 512
#define OUT_FEAT 128

// NUMERICS CONTRACT (R3 post-mortem): fp32 accumulation order must be
// strictly sequential (k-order in GEMM, edge-order in SPMM). Reassociation
// flips floor() boundaries in multispike -> absmax 0.25. Get MLP from
// batched independent loads feeding ONE in-order FMA chain per output.

__device__ __forceinline__ float multispike(float a) {
    // floor(clamp(4x, 0, 4) + 0.5) / 4
    return floorf(fminf(fmaxf(4.0f * a, 0.0f), 4.0f) + 0.5f) * 0.25f;
}

// ---------------------------------------------------------------------------
// GEMM, LDS-free (R4 post-mortem: classic tile structure is LDS-pipe-bound
// on this shape; R2 prefetch + R4 retile both failed to fix it).
// Wave owns 16 rows x all 128 cols. A[m][k] is wave-uniform -> s_load into
// SGPRs (scalar cache pipe, free). B[k][n] -> coalesced global float2 per
// lane (B = 256 KB, L1/L2 resident). acc[16] float2 in VGPRs, k strictly
// sequential. No LDS, no barriers, no bank conflicts.
// Per wave-k-step: 32 v_fma (16 CU-cyc) vs 512B B-load (~8 cyc L1) -> FMA-bound.
// ---------------------------------------------------------------------------
__global__ __launch_bounds__(256) void gemm_kernel(const float* __restrict__ A,
                                                   const float* __restrict__ B,
                                                   float* __restrict__ C, int M) {
    const int lane = threadIdx.x & 63;
    // force wave-id into an SGPR so all A addressing is provably uniform
    const int wv = __builtin_amdgcn_readfirstlane(threadIdx.x >> 6);
    const int row0 = blockIdx.x * 64 + wv * 16;

    const float2* __restrict__ B2 = (const float2*)B;

    // per-row uniform base pointers (SGPR pairs); clamp OOB rows to a valid
    // address (results discarded by the store guard)
    const float* Ar[16];
#pragma unroll
    for (int m = 0; m < 16; m++) {
        int r = row0 + m;
        if (r > M - 1) r = M - 1;
        Ar[m] = A + (size_t)r * IN_FEAT;
    }

    float2 acc[16];
#pragma unroll
    for (int m = 0; m < 16; m++) acc[m] = make_float2(0.f, 0.f);

    for (int k0 = 0; k0 < IN_FEAT; k0 += 4) {
        // 4 coalesced B row-slices (independent loads, issued together)
        float2 b0 = B2[(size_t)(k0 + 0) * 64 + lane];
        float2 b1 = B2[(size_t)(k0 + 1) * 64 + lane];
        float2 b2 = B2[(size_t)(k0 + 2) * 64 + lane];
        float2 b3 = B2[(size_t)(k0 + 3) * 64 + lane];
#pragma unroll
        for (int m = 0; m < 16; m++) {
            // uniform 16B load -> s_load_dwordx4 (scalar pipe)
            float4 a = *(const float4*)(Ar[m] + k0);
            // strict k-order accumulation within each output
            acc[m].x = fmaf(a.x, b0.x, acc[m].x);
            acc[m].y = fmaf(a.x, b0.y, acc[m].y);
            acc[m].x = fmaf(a.y, b1.x, acc[m].x);
            acc[m].y = fmaf(a.y, b1.y, acc[m].y);
            acc[m].x = fmaf(a.z, b2.x, acc[m].x);
            acc[m].y = fmaf(a.z, b2.y, acc[m].y);
            acc[m].x = fmaf(a.w, b3.x, acc[m].x);
            acc[m].y = fmaf(a.w, b3.y, acc[m].y);
        }
    }

    float2* __restrict__ C2 = (float2*)C;
#pragma unroll
    for (int m = 0; m < 16; m++) {
        int r = row0 + m;
        if (r < M) C2[(size_t)r * 64 + lane] = acc[m];
    }
}

// ---------------------------------------------------------------------------
// row_ptr[i] = lower_bound(rows, i) over sorted rows. i in [0, N_NODES].
// ---------------------------------------------------------------------------
__global__ __launch_bounds__(256) void rowptr_kernel(const int* __restrict__ rows,
                                                     int* __restrict__ row_ptr) {
    int i = blockIdx.x * blockDim.x + threadIdx.x;
    if (i > N_NODES) return;
    int lo = 0, hi = N_EDGES;
    while (lo < hi) {
        int mid = (lo + hi) >> 1;
        if (rows[mid] < i) lo = mid + 1; else hi = mid;
    }
    row_ptr[i] = lo;
}

// ---------------------------------------------------------------------------
// SPMM + multispike (unchanged from R4 - numerics-proven, absmax 0.0):
// one wave per output row, lane owns float2. Unroll x8 batched loads,
// ONE in-order FMA chain per accumulator (reference edge order).
// ---------------------------------------------------------------------------
__global__ __launch_bounds__(256) void spmm_kernel(const float* __restrict__ x,
                                                   const int* __restrict__ cols,
                                                   const float* __restrict__ ew,
                                                   const int* __restrict__ row_ptr,
                                                   float* __restrict__ out) {
    const int wave = threadIdx.x >> 6;
    const int lane = threadIdx.x & 63;
    const int r = blockIdx.x * 4 + wave;
    if (r >= N_NODES) return;

    const int e0 = row_ptr[r];
    const int e1 = row_ptr[r + 1];
    const float2* __restrict__ x2 = (const float2*)x;

    float accx = 0.0f, accy = 0.0f;
    int e = e0;
    for (; e + 8 <= e1; e += 8) {
        int c[8];
        float w[8];
        float2 v[8];
#pragma unroll
        for (int j = 0; j < 8; j++) {
            c[j] = cols[e + j];
            w[j] = ew[e + j];
        }
#pragma unroll
        for (int j = 0; j < 8; j++) {
            v[j] = x2[(size_t)c[j] * 64 + lane];
        }
#pragma unroll
        for (int j = 0; j < 8; j++) {   // strict e-order accumulation
            accx = fmaf(w[j], v[j].x, accx);
            accy = fmaf(w[j], v[j].y, accy);
        }
    }
    for (; e < e1; e++) {
        int c = cols[e];
        float w = ew[e];
        float2 v = x2[(size_t)c * 64 + lane];
        accx = fmaf(w, v.x, accx);
        accy = fmaf(w, v.y, accy);
    }
    float2* out2 = (float2*)out;
    out2[(size_t)r * 64 + lane] = make_float2(multispike(accx), multispike(accy));
}

extern "C" void kernel_launch(void* const* d_in, const int* in_sizes, int n_in,
                              void* d_out, int out_size, void* d_ws, size_t ws_size,
                              hipStream_t stream) {
    const float* feat = (const float*)d_in[0];   // [50000, 512]
    const float* weight = (const float*)d_in[1]; // [512, 128]
    const int* rows = (const int*)d_in[2];       // [800000] sorted
    const int* cols = (const int*)d_in[3];       // [800000]
    const float* ew = (const float*)d_in[4];     // [800000]
    float* out = (float*)d_out;                  // [50000, 128]

    // Workspace layout: x [50000*128 f32] then row_ptr [50001 i32]
    float* x = (float*)d_ws;
    int* row_ptr = (int*)((char*)d_ws + (size_t)N_NODES * OUT_FEAT * sizeof(float));

    rowptr_kernel<<<(N_NODES + 256) / 256, 256, 0, stream>>>(rows, row_ptr);
    gemm_kernel<<<(N_NODES + 63) / 64, 256, 0, stream>>>(feat, weight, x, N_NODES);
    spmm_kernel<<<(N_NODES + 3) / 4, 256, 0, stream>>>(x, cols, ew, row_ptr, out);
}

// Round 6
// 335.955 us; speedup vs baseline: 1.5336x; 1.5336x over previous
//
#include <hip/hip_runtime.h>

#define N_NODES 50000
#define N_EDGES 800000
#define IN_FEAT 512
#define OUT_FEAT 128

// NUMERICS CONTRACT (R3 post-mortem): fp32 accumulation order must be
// strictly sequential (k-order in GEMM, edge-order in SPMM). Reassociation
// flips floor() boundaries in multispike -> absmax 0.25. Get MLP from
// batched independent loads feeding ONE in-order FMA chain per output.
//
// COMPILER CONTRACT (R5 post-mortem): no indexed per-thread pointer/acc
// arrays with dynamic-looking indices -> scratch demotion (VGPR=24, 335us).
// Keep register arrays fully-unrolled with constant indices.

__device__ __forceinline__ float multispike(float a) {
    // floor(clamp(4x, 0, 4) + 0.5) / 4
    return floorf(fminf(fmaxf(4.0f * a, 0.0f), 4.0f) + 0.5f) * 0.25f;
}

// ---------------------------------------------------------------------------
// GEMM: C[M,128] = A[M,512] @ B[512,128], fp32 vector FMA.
// BM=64, BN=128, BK=32, 256 threads, thread tile 8x4 (R1 structure - the
// measured-best baseline, 125.6us).
// R6 change: B is NOT staged in LDS. The BK=32 B-slice is 16 KB and
// L1-resident (B total = 256 KB); each k-step reads B[k][tx*4..] as one
// global_load_dwordx4 on the VMEM pipe. LDS ledger per CU per k-tile drops
// ~15000 -> ~9770 cyc (R1's VALUBusy=41.5% exactly matched the 6144/15000
// FMA:LDS ratio -> kernel is LDS-pipe-bound). Same operands, same k-order
// -> bit-identical numerics to R1.
// As padded to 68 (R2-proven: conflicts 5.6M->2.4M), rows 16B-aligned.
// ---------------------------------------------------------------------------
__global__ __launch_bounds__(256) void gemm_kernel(const float* __restrict__ A,
                                                   const float* __restrict__ B,
                                                   float* __restrict__ C, int M) {
    __shared__ float As[32][68];    // [k][m], padded

    const int tid = threadIdx.x;
    const int tx = tid & 31;   // n = tx*4 .. tx*4+3
    const int ty = tid >> 5;   // m = ty*8 .. ty*8+7
    const int block_m = blockIdx.x * 64;

    const float4* __restrict__ B4 = (const float4*)B;   // row stride 32 float4s

    float acc[8][4];
#pragma unroll
    for (int i = 0; i < 8; i++)
#pragma unroll
        for (int j = 0; j < 4; j++) acc[i][j] = 0.0f;

    for (int k0 = 0; k0 < IN_FEAT; k0 += 32) {
        // Stage A tile: 64 rows x 32 k = 512 float4 / 256 threads = 2 each.
        // Coalesced global read, transposed LDS store (4-way conflict w/ pad).
#pragma unroll
        for (int i = 0; i < 2; i++) {
            int f = tid + i * 256;
            int r = f >> 3;
            int kq = (f & 7) << 2;
            int gm = block_m + r;
            float4 v = make_float4(0.f, 0.f, 0.f, 0.f);
            if (gm < M) v = *(const float4*)(A + (size_t)gm * IN_FEAT + k0 + kq);
            As[kq + 0][r] = v.x;
            As[kq + 1][r] = v.y;
            As[kq + 2][r] = v.z;
            As[kq + 3][r] = v.w;
        }
        __syncthreads();

#pragma unroll
        for (int k = 0; k < 32; k++) {
            // B row-slice straight from global (L1-resident, VMEM pipe)
            float4 b = B4[(size_t)(k0 + k) * 32 + tx];
            float4 a0 = *(const float4*)&As[k][ty * 8];
            float4 a1 = *(const float4*)&As[k][ty * 8 + 4];
            float av[8] = {a0.x, a0.y, a0.z, a0.w, a1.x, a1.y, a1.z, a1.w};
            float bv[4] = {b.x, b.y, b.z, b.w};
#pragma unroll
            for (int i = 0; i < 8; i++)
#pragma unroll
                for (int j = 0; j < 4; j++)
                    acc[i][j] = fmaf(av[i], bv[j], acc[i][j]);
        }
        __syncthreads();
    }

#pragma unroll
    for (int i = 0; i < 8; i++) {
        int gm = block_m + ty * 8 + i;
        if (gm < M) {
            float4 v = make_float4(acc[i][0], acc[i][1], acc[i][2], acc[i][3]);
            *(float4*)(C + (size_t)gm * OUT_FEAT + tx * 4) = v;
        }
    }
}

// ---------------------------------------------------------------------------
// row_ptr[i] = lower_bound(rows, i) over sorted rows. i in [0, N_NODES].
// ---------------------------------------------------------------------------
__global__ __launch_bounds__(256) void rowptr_kernel(const int* __restrict__ rows,
                                                     int* __restrict__ row_ptr) {
    int i = blockIdx.x * blockDim.x + threadIdx.x;
    if (i > N_NODES) return;
    int lo = 0, hi = N_EDGES;
    while (lo < hi) {
        int mid = (lo + hi) >> 1;
        if (rows[mid] < i) lo = mid + 1; else hi = mid;
    }
    row_ptr[i] = lo;
}

// ---------------------------------------------------------------------------
// SPMM + multispike (unchanged, numerics-proven absmax 0.0): one wave per
// output row, lane owns float2. Unroll x8 batched loads, ONE in-order FMA
// chain per accumulator (reference edge order).
// ---------------------------------------------------------------------------
__global__ __launch_bounds__(256) void spmm_kernel(const float* __restrict__ x,
                                                   const int* __restrict__ cols,
                                                   const float* __restrict__ ew,
                                                   const int* __restrict__ row_ptr,
                                                   float* __restrict__ out) {
    const int wave = threadIdx.x >> 6;
    const int lane = threadIdx.x & 63;
    const int r = blockIdx.x * 4 + wave;
    if (r >= N_NODES) return;

    const int e0 = row_ptr[r];
    const int e1 = row_ptr[r + 1];
    const float2* __restrict__ x2 = (const float2*)x;

    float accx = 0.0f, accy = 0.0f;
    int e = e0;
    for (; e + 8 <= e1; e += 8) {
        int c[8];
        float w[8];
        float2 v[8];
#pragma unroll
        for (int j = 0; j < 8; j++) {
            c[j] = cols[e + j];
            w[j] = ew[e + j];
        }
#pragma unroll
        for (int j = 0; j < 8; j++) {
            v[j] = x2[(size_t)c[j] * 64 + lane];
        }
#pragma unroll
        for (int j = 0; j < 8; j++) {   // strict e-order accumulation
            accx = fmaf(w[j], v[j].x, accx);
            accy = fmaf(w[j], v[j].y, accy);
        }
    }
    for (; e < e1; e++) {
        int c = cols[e];
        float w = ew[e];
        float2 v = x2[(size_t)c * 64 + lane];
        accx = fmaf(w, v.x, accx);
        accy = fmaf(w, v.y, accy);
    }
    float2* out2 = (float2*)out;
    out2[(size_t)r * 64 + lane] = make_float2(multispike(accx), multispike(accy));
}

extern "C" void kernel_launch(void* const* d_in, const int* in_sizes, int n_in,
                              void* d_out, int out_size, void* d_ws, size_t ws_size,
                              hipStream_t stream) {
    const float* feat = (const float*)d_in[0];   // [50000, 512]
    const float* weight = (const float*)d_in[1]; // [512, 128]
    const int* rows = (const int*)d_in[2];       // [800000] sorted
    const int* cols = (const int*)d_in[3];       // [800000]
    const float* ew = (const float*)d_in[4];     // [800000]
    float* out = (float*)d_out;                  // [50000, 128]

    // Workspace layout: x [50000*128 f32] then row_ptr [50001 i32]
    float* x = (float*)d_ws;
    int* row_ptr = (int*)((char*)d_ws + (size_t)N_NODES * OUT_FEAT * sizeof(float));

    rowptr_kernel<<<(N_NODES + 256) / 256, 256, 0, stream>>>(rows, row_ptr);
    gemm_kernel<<<(N_NODES + 63) / 64, 256, 0, stream>>>(feat, weight, x, N_NODES);
    spmm_kernel<<<(N_NODES + 3) / 4, 256, 0, stream>>>(x, cols, ew, row_ptr, out);
}